// Round 1
// baseline (74.364 us; speedup 1.0000x reference)
//
#include <hip/hip_runtime.h>

// Chamfer distance, fp32, A,B = [4][8192][3].
// Stage 1: for each (dir, batch, row) compute min over cols of
//   ||a-b||^2 = a2 + (b2 - 2 a.b), tracked as acc = min(b2 - 2 a.b),
//   row result = max(a2 + acc, 0), combined across m-blocks via uint atomicMin.
// Stage 2: out = sum(sqrt(rowmin)) / (NB * NPTS * 12.8).

constexpr int NB    = 4;
constexpr int NPTS  = 8192;
constexpr int R     = 8;                 // rows per lane
constexpr int ROWS_PER_BLOCK = 64 * R;   // 512
constexpr int MSLICE = 1024;             // cols staged per block
constexpr int WAVES  = 4;                // 256 threads
constexpr int COLS_PER_WAVE = MSLICE / WAVES;  // 256
constexpr int ROWBLKS = NPTS / ROWS_PER_BLOCK; // 16
constexpr int MBLKS   = NPTS / MSLICE;         // 8

__global__ __launch_bounds__(256, 4)
void chamfer_min_kernel(const float* __restrict__ A,
                        const float* __restrict__ B,
                        unsigned int* __restrict__ ws_min) {
    int bid = blockIdx.x;
    int dir    = bid & 1;            bid >>= 1;
    int mblk   = bid & (MBLKS - 1);  bid >>= 3;
    int rowblk = bid & (ROWBLKS - 1); bid >>= 4;
    int batch  = bid;

    const float* rows = (dir == 0 ? A : B) + batch * NPTS * 3;
    const float* cols = (dir == 0 ? B : A) + batch * NPTS * 3;
    unsigned int* out_min = ws_min + (dir * NB + batch) * NPTS;

    __shared__ float4 tup[MSLICE];   // (-2bx, -2by, -2bz, b2)  -> 16 KB

    // Stage the column tuples for this m-block.
    int mbase = mblk * MSLICE;
    for (int i = threadIdx.x; i < MSLICE; i += 256) {
        int m = mbase + i;
        float bx = cols[m * 3 + 0];
        float by = cols[m * 3 + 1];
        float bz = cols[m * 3 + 2];
        tup[i] = make_float4(-2.0f * bx, -2.0f * by, -2.0f * bz,
                             bx * bx + by * by + bz * bz);
    }
    __syncthreads();

    int lane = threadIdx.x & 63;
    int wave = threadIdx.x >> 6;
    int rowbase = rowblk * ROWS_PER_BLOCK;

    float ax[R], ay[R], az[R], a2[R], acc[R];
    #pragma unroll
    for (int r = 0; r < R; ++r) {
        int row = rowbase + r * 64 + lane;
        ax[r] = rows[row * 3 + 0];
        ay[r] = rows[row * 3 + 1];
        az[r] = rows[row * 3 + 2];
        a2[r] = ax[r] * ax[r] + ay[r] * ay[r] + az[r] * az[r];
        acc[r] = 3.0e38f;
    }

    // Each wave sweeps its own 256-column sub-slice (broadcast LDS reads).
    const float4* tw = tup + wave * COLS_PER_WAVE;
    #pragma unroll 4
    for (int i = 0; i < COLS_PER_WAVE; ++i) {
        float4 t = tw[i];
        #pragma unroll
        for (int r = 0; r < R; ++r) {
            float v = fmaf(az[r], t.z, t.w);
            v = fmaf(ay[r], t.y, v);
            v = fmaf(ax[r], t.x, v);
            acc[r] = fminf(acc[r], v);
        }
    }

    #pragma unroll
    for (int r = 0; r < R; ++r) {
        float v = fmaxf(a2[r] + acc[r], 0.0f);   // >= 0, so uint order == float order
        atomicMin(&out_min[rowbase + r * 64 + lane], __float_as_uint(v));
    }
}

__global__ __launch_bounds__(1024)
void chamfer_reduce_kernel(const unsigned int* __restrict__ ws_min,
                           float* __restrict__ out) {
    __shared__ float red[16];
    float s = 0.0f;
    for (int i = threadIdx.x; i < 2 * NB * NPTS; i += 1024)
        s += sqrtf(__uint_as_float(ws_min[i]));
    #pragma unroll
    for (int off = 32; off >= 1; off >>= 1)
        s += __shfl_down(s, off, 64);
    int lane = threadIdx.x & 63;
    int wave = threadIdx.x >> 6;
    if (lane == 0) red[wave] = s;
    __syncthreads();
    if (threadIdx.x == 0) {
        float tot = 0.0f;
        #pragma unroll
        for (int w = 0; w < 16; ++w) tot += red[w];
        out[0] = tot * (1.0f / (NB * NPTS * 12.8f));
    }
}

extern "C" void kernel_launch(void* const* d_in, const int* in_sizes, int n_in,
                              void* d_out, int out_size, void* d_ws, size_t ws_size,
                              hipStream_t stream) {
    const float* A = (const float*)d_in[0];
    const float* B = (const float*)d_in[1];
    float* out = (float*)d_out;
    unsigned int* wsm = (unsigned int*)d_ws;

    // Init row-min workspace to 0xFFFFFFFF (> any non-negative float as uint).
    hipMemsetAsync(d_ws, 0xFF, (size_t)(2 * NB * NPTS) * sizeof(unsigned int), stream);

    chamfer_min_kernel<<<2 * NB * ROWBLKS * MBLKS, 256, 0, stream>>>(A, B, wsm);
    chamfer_reduce_kernel<<<1, 1024, 0, stream>>>(wsm, out);
}

// Round 2
// 57.030 us; speedup vs baseline: 1.3040x; 1.3040x over previous
//
#include <hip/hip_runtime.h>

// Chamfer distance, fp32, A,B = [4][8192][3].
// Stage 1: row-mins of ||a-b||^2 via acc = min(b2 - 2 a.b), software-pipelined
//          2 columns/iter with min3 fusion; cross-m-block combine via uint atomicMin.
// Stage 2: 64-block parallel sqrt+sum, one float atomicAdd per block.

constexpr int NB    = 4;
constexpr int NPTS  = 8192;
constexpr int R     = 8;                 // rows per lane
constexpr int ROWS_PER_BLOCK = 64 * R;   // 512
constexpr int MSLICE = 1024;             // cols staged per block
constexpr int WAVES  = 4;                // 256 threads
constexpr int COLS_PER_WAVE = MSLICE / WAVES;  // 256
constexpr int ROWBLKS = NPTS / ROWS_PER_BLOCK; // 16
constexpr int MBLKS   = NPTS / MSLICE;         // 8

__global__ __launch_bounds__(256, 4)
void chamfer_min_kernel(const float* __restrict__ A,
                        const float* __restrict__ B,
                        unsigned int* __restrict__ ws_min) {
    int bid = blockIdx.x;
    int dir    = bid & 1;             bid >>= 1;
    int mblk   = bid & (MBLKS - 1);   bid >>= 3;
    int rowblk = bid & (ROWBLKS - 1); bid >>= 4;
    int batch  = bid;

    const float* rows = (dir == 0 ? A : B) + batch * NPTS * 3;
    const float* cols = (dir == 0 ? B : A) + batch * NPTS * 3;
    unsigned int* out_min = ws_min + (dir * NB + batch) * NPTS;

    __shared__ float4 tup[MSLICE + 2];   // (-2bx, -2by, -2bz, b2), +2 pad for prefetch

    int mbase = mblk * MSLICE;
    for (int i = threadIdx.x; i < MSLICE; i += 256) {
        int m = mbase + i;
        float bx = cols[m * 3 + 0];
        float by = cols[m * 3 + 1];
        float bz = cols[m * 3 + 2];
        tup[i] = make_float4(-2.0f * bx, -2.0f * by, -2.0f * bz,
                             bx * bx + by * by + bz * bz);
    }
    __syncthreads();

    int lane = threadIdx.x & 63;
    int wave = threadIdx.x >> 6;
    int rowbase = rowblk * ROWS_PER_BLOCK;

    float ax[R], ay[R], az[R], acc[R];
    #pragma unroll
    for (int r = 0; r < R; ++r) {
        int row = rowbase + r * 64 + lane;
        ax[r] = rows[row * 3 + 0];
        ay[r] = rows[row * 3 + 1];
        az[r] = rows[row * 3 + 2];
        acc[r] = 3.0e38f;
    }

    // 2 columns per iteration, next pair prefetched into registers.
    const float4* tw = tup + wave * COLS_PER_WAVE;
    float4 t0 = tw[0];
    float4 t1 = tw[1];
    #pragma unroll 2
    for (int i = 0; i < COLS_PER_WAVE - 2; i += 2) {
        float4 p0 = tw[i + 2];
        float4 p1 = tw[i + 3];
        #pragma unroll
        for (int r = 0; r < R; ++r) {
            float v0 = fmaf(ax[r], t0.x, fmaf(ay[r], t0.y, fmaf(az[r], t0.z, t0.w)));
            float v1 = fmaf(ax[r], t1.x, fmaf(ay[r], t1.y, fmaf(az[r], t1.z, t1.w)));
            acc[r] = fminf(acc[r], fminf(v0, v1));   // -> v_min3_f32
        }
        t0 = p0; t1 = p1;
    }
    #pragma unroll
    for (int r = 0; r < R; ++r) {
        float v0 = fmaf(ax[r], t0.x, fmaf(ay[r], t0.y, fmaf(az[r], t0.z, t0.w)));
        float v1 = fmaf(ax[r], t1.x, fmaf(ay[r], t1.y, fmaf(az[r], t1.z, t1.w)));
        acc[r] = fminf(acc[r], fminf(v0, v1));
    }

    #pragma unroll
    for (int r = 0; r < R; ++r) {
        float a2 = fmaf(ax[r], ax[r], fmaf(ay[r], ay[r], az[r] * az[r]));
        float v = fmaxf(a2 + acc[r], 0.0f);   // >= 0: uint order == float order
        atomicMin(&out_min[rowbase + r * 64 + lane], __float_as_uint(v));
    }
}

__global__ __launch_bounds__(256)
void chamfer_reduce_kernel(const unsigned int* __restrict__ ws_min,
                           float* __restrict__ out) {
    constexpr float SCALE = 1.0f / (NB * NPTS * 12.8f);
    int idx = (blockIdx.x * 256 + threadIdx.x) * 4;
    uint4 v = *reinterpret_cast<const uint4*>(ws_min + idx);
    float s = sqrtf(__uint_as_float(v.x)) + sqrtf(__uint_as_float(v.y))
            + sqrtf(__uint_as_float(v.z)) + sqrtf(__uint_as_float(v.w));
    #pragma unroll
    for (int off = 32; off >= 1; off >>= 1)
        s += __shfl_down(s, off, 64);
    __shared__ float red[4];
    if ((threadIdx.x & 63) == 0) red[threadIdx.x >> 6] = s;
    __syncthreads();
    if (threadIdx.x == 0) {
        float tot = (red[0] + red[1]) + (red[2] + red[3]);
        atomicAdd(out, tot * SCALE);
    }
}

extern "C" void kernel_launch(void* const* d_in, const int* in_sizes, int n_in,
                              void* d_out, int out_size, void* d_ws, size_t ws_size,
                              hipStream_t stream) {
    const float* A = (const float*)d_in[0];
    const float* B = (const float*)d_in[1];
    float* out = (float*)d_out;
    unsigned int* wsm = (unsigned int*)d_ws;

    hipMemsetAsync(d_ws, 0xFF, (size_t)(2 * NB * NPTS) * sizeof(unsigned int), stream);
    hipMemsetAsync(d_out, 0, sizeof(float), stream);

    chamfer_min_kernel<<<2 * NB * ROWBLKS * MBLKS, 256, 0, stream>>>(A, B, wsm);
    // 2*NB*NPTS = 65536 mins; 64 blocks x 256 threads x 4 each
    chamfer_reduce_kernel<<<64, 256, 0, stream>>>(wsm, out);
}